// Round 12
// baseline (223.709 us; speedup 1.0000x reference)
//
#include <hip/hip_runtime.h>

#define BB 4
#define CC 256
#define DD 32
#define SS 4096

typedef __bf16 bf16;
typedef __bf16 bf16x8 __attribute__((ext_vector_type(8)));
typedef __bf16 bf16x4 __attribute__((ext_vector_type(4)));
typedef float f32x4 __attribute__((ext_vector_type(4)));
typedef unsigned int u32;
typedef u32 u32x4 __attribute__((ext_vector_type(4)));
typedef unsigned short u16;

// workspace layout (bf16 elements):
//  q:  [2][BB][SS][DD]  off 0         (pos-major, 32 d inner)
//  k:  [2][BB][SS][DD]  off 1048576
//  v:  [2][BB][...]     off 2097152   chunked B-frag order: V[c][key] at
//       (2*(key>>6) + ks)*8192 + (c>>4)*512 + (quadf*16 + (c&15))*8 + j
//       (kk=key&63, ks=kk>>5, quadf=(kk>>2)&3, j=((kk>>4)&1)*4+(kk&3));
//       each 1 KB fragment lane-contiguous; each 32 KB chunk contiguous.
//       TRANSIENT ALIAS: prep writes X^T A-frag tiles here first; proj block
//       (dirb,tile) DMA-reads slice [tile*16384,+16384) into LDS, then
//       overwrites exactly that slice with V output (slice-exact, safe).
//  wb: [320][CC]        off 10485760  (bf16 Wq|Wk|Wv stacked)
#define Q_OFF  0
#define K_OFF  1048576
#define V_OFF  2097152
#define WB_OFF 10485760
#define CH_ELEM 16384   // elements per 64-key V chunk / per X^T tile (32 KB)

static __device__ __forceinline__ u32 pack2(float lo, float hi) {
    bf16 a = (bf16)lo, b = (bf16)hi;
    u16 ua = __builtin_bit_cast(u16, a), ub = __builtin_bit_cast(u16, b);
    return (u32)ua | ((u32)ub << 16);
}

// staged-buffer barrier: wait until only the 12 newest VMEM ops (next chunk's
// 8 staging + the K prefetch quad) remain in flight (T4 counted-vmcnt).
static __device__ __forceinline__ void bar_vm12() {
    asm volatile("s_waitcnt vmcnt(12)" ::: "memory");
    __builtin_amdgcn_s_barrier();
    asm volatile("" ::: "memory");
}
static __device__ __forceinline__ void bar_plain() {
    asm volatile("" ::: "memory");
    __builtin_amdgcn_s_barrier();
    asm volatile("" ::: "memory");
}

// ------------------------------------------------- prep: W fp32->bf16 + X^T tiles
// Blocks 0..511: transpose (src,b,tile) X fp32 -> bf16 A-frag tile into the
// V region (transient alias). Blocks 512..551: convert W -> wb [320][256].
// Lane map chosen so every wave STORE is a contiguous 1 KB block (R11's map
// scattered 16B stores at 64B stride -> ~4x write amplification, ~50 us).
__global__ __launch_bounds__(256) void prep_kernel(
    const float* __restrict__ x, const float* __restrict__ y,
    const float* __restrict__ Wq, const float* __restrict__ Wk,
    const float* __restrict__ Wv,
    bf16* __restrict__ xb, bf16* __restrict__ wb)
{
    const int t   = threadIdx.x;
    const int bid = blockIdx.x;

    if (bid >= 512) {
        const int gid = (bid - 512)*256 + t;         // 40 blocks -> 10240
        const int idx = gid*8;
        const int o = idx >> 8, cc = idx & 255;
        const float* row = (o < 32) ? (Wq + (size_t)o*CC)
                         : (o < 64) ? (Wk + (size_t)(o-32)*CC)
                                    : (Wv + (size_t)(o-64)*CC);
        const float4 a = *(const float4*)(row + cc);
        const float4 c = *(const float4*)(row + cc + 4);
        bf16x8 pk;
        pk[0]=(bf16)a.x; pk[1]=(bf16)a.y; pk[2]=(bf16)a.z; pk[3]=(bf16)a.w;
        pk[4]=(bf16)c.x; pk[5]=(bf16)c.y; pk[6]=(bf16)c.z; pk[7]=(bf16)c.w;
        *(bf16x8*)(wb + idx) = pk;
        return;
    }

    // transpose: element (pos,cc) -> tile*16384 + pb*4096 + co*512 + quadf*128
    // + ln*8 + j   where pos = pb*16+ln (in tile), cc = 8*quadf + 32*co + j.
    // Lane = (ln, quadf); loop (co in wave's pair, pb): wave stores 64x16B
    // CONTIGUOUS (1 KB); reads are 16-lane x 64B contiguous per (quadf,j).
    const int dirb = bid & 7;
    const int src  = dirb >> 2;
    const int b    = dirb & 3;
    const int tile = bid >> 3;                    // 0..63
    const float* in = (src ? y : x) + (size_t)b*CC*SS + tile*64;
    bf16* outp = xb + (size_t)dirb*1048576 + (size_t)tile*CH_ELEM;

    const int ln    = t & 15;
    const int quadf = (t >> 4) & 3;
    const int w     = t >> 6;
    #pragma unroll
    for (int cop = 0; cop < 2; ++cop) {
        const int co = w*2 + cop;
        #pragma unroll
        for (int pb = 0; pb < 4; ++pb) {
            float f[8];
            #pragma unroll
            for (int j = 0; j < 8; ++j)
                f[j] = in[(size_t)(8*quadf + 32*co + j)*SS + pb*16 + ln];
            bf16x8 pk;
            #pragma unroll
            for (int j = 0; j < 8; ++j) pk[j] = (bf16)f[j];
            *(bf16x8*)(outp + pb*4096 + co*512 + quadf*128 + ln*8) = pk;
        }
    }
}

// ------------------------------------------------- fused q,k,v projection (MFMA)
// C[pos][o] = sum_cc X[cc][pos]*W[o][cc] + bias;  o: 0-31 q, 32-63 k, 64-319 v
// X^T tile (64 pos x 256 cc, A-frag order) DMA-staged to LDS in one shot
// (global_load_lds x8/thread), ONE barrier, then 8 chunks x 20 MFMA per wave
// straight through (conflict-free ds_read_b128, W prefetched from L2).
// Reads its xb slice from the V region and overwrites the SAME slice with V.
__global__ __launch_bounds__(256, 2) void proj_all_kernel(
    const bf16* __restrict__ xb, const bf16* __restrict__ wb,
    const float* __restrict__ bq, const float* __restrict__ bk,
    const float* __restrict__ bv,
    bf16* __restrict__ qout, bf16* __restrict__ kout, bf16* __restrict__ vout)
{
    __shared__ __align__(16) char xsm[32768];

    const int t    = threadIdx.x;
    const int lane = t & 63;
    const int w    = t >> 6;
    const int ln   = lane & 15;
    const int quad = lane >> 4;

    const int bid  = blockIdx.x;
    const int dirb = bid & 7;
    const int src  = dirb >> 2;
    const int b    = dirb & 3;
    const int tile = bid >> 3;
    const int i0   = tile * 64;

    // DMA stage the whole X^T tile (32 KB, linear)
    {
        const bf16* xstage = xb + (size_t)dirb*1048576 + (size_t)tile*CH_ELEM
                             + w*512 + lane*8;
        char* ldsb = xsm + w*1024;
        #pragma unroll
        for (int j = 0; j < 8; ++j)
            __builtin_amdgcn_global_load_lds(
                (const __attribute__((address_space(1))) void*)(xstage + j*2048),
                (__attribute__((address_space(3))) void*)(ldsb + j*4096),
                16, 0, 0);
    }

    float bias[5];
    #pragma unroll
    for (int nbl = 0; nbl < 5; ++nbl) {
        const int o = 80*w + nbl*16 + ln;
        bias[nbl] = (o < 32) ? bq[o] : (o < 64) ? bk[o-32] : bv[o-64];
    }
    const bf16* wrow = wb + (size_t)(80*w + ln)*CC + quad*8;
    bf16x8 bf[5];
    #pragma unroll
    for (int nbl = 0; nbl < 5; ++nbl)
        bf[nbl] = *(const bf16x8*)(wrow + (size_t)nbl*16*CC);

    f32x4 acc[4][5];
    #pragma unroll
    for (int mb = 0; mb < 4; ++mb)
        #pragma unroll
        for (int nbl = 0; nbl < 5; ++nbl)
            acc[mb][nbl] = (f32x4){bias[nbl], bias[nbl], bias[nbl], bias[nbl]};

    __syncthreads();   // DMA complete (vmcnt(0) drain is fine here: one-shot)

    for (int n = 0; n < 8; ++n) {
        bf16x8 af[4];
        #pragma unroll
        for (int mb = 0; mb < 4; ++mb)
            af[mb] = *(const bf16x8*)(xsm + mb*8192 + n*1024 + lane*16);
        #pragma unroll
        for (int mb = 0; mb < 4; ++mb)
            #pragma unroll
            for (int nbl = 0; nbl < 5; ++nbl)
                acc[mb][nbl] = __builtin_amdgcn_mfma_f32_16x16x32_bf16(
                                   af[mb], bf[nbl], acc[mb][nbl], 0, 0, 0);
        // prefetch next W chunk (wrap at tail: redundant, in-bounds)
        const int ccn = ((n+1)*32) & 255;
        #pragma unroll
        for (int nbl = 0; nbl < 5; ++nbl)
            bf[nbl] = *(const bf16x8*)(wrow + (size_t)nbl*16*CC + ccn);
    }

    bf16* qo = qout + (size_t)(src*BB + b)*SS*DD;
    bf16* ko = kout + (size_t)(src*BB + b)*SS*DD;
    bf16* vo = vout + (size_t)(src*BB + b)*CC*SS;
    const int n0 = tile;
    #pragma unroll
    for (int nbl = 0; nbl < 5; ++nbl) {
        const int o = 80*w + nbl*16 + ln;
        if (o < 32) {
            #pragma unroll
            for (int mb = 0; mb < 4; ++mb)
                #pragma unroll
                for (int r = 0; r < 4; ++r)
                    qo[(size_t)(i0 + mb*16 + quad*4 + r)*DD + o] = (bf16)acc[mb][nbl][r];
        } else if (o < 64) {
            #pragma unroll
            for (int mb = 0; mb < 4; ++mb)
                #pragma unroll
                for (int r = 0; r < 4; ++r)
                    ko[(size_t)(i0 + mb*16 + quad*4 + r)*DD + (o-32)] = (bf16)acc[mb][nbl][r];
        } else {
            const int c = o - 64;
            const int cb = c >> 4, cl = c & 15;
            // pos = i0+mb*16+quad*4+r -> chunk n0, ks=mb>>1, j=(mb&1)*4+r,
            // quadf=quad -> contiguous bf16x4 store within lane's 16B slot
            #pragma unroll
            for (int mb = 0; mb < 4; ++mb) {
                bf16x4 pk;
                #pragma unroll
                for (int r = 0; r < 4; ++r) pk[r] = (bf16)acc[mb][nbl][r];
                *(bf16x4*)(vo + (size_t)(2*n0 + (mb>>1))*8192 + cb*512
                              + (quad*16 + cl)*8 + (mb&1)*4) = pk;
            }
        }
    }
}

// ------------------------------------------------- attention (LDS-staged V, private P)
// R11 verified structure (119.7 us, MfmaUtil 28%, 0 conflicts, VGPR 88):
// bar_vm12 -> PV(n) [ds_read+MFMA issue immediately] -> S^T(n+1) -> bar_plain
// -> STAGE(n+2) -> SMAX(n+1) (in the shadow of the next staging wait).
#define L2E   1.4426950408889634f
#define SM_C  (16.0f * L2E)

__global__ __launch_bounds__(256, 2) void attn_kernel(
    const bf16* __restrict__ qg, const bf16* __restrict__ kg,
    const bf16* __restrict__ vg, float* __restrict__ out)
{
    __shared__ __align__(16) char vsm[2*32768];   // V chunk double buffer

    const int t    = threadIdx.x;
    const int lane = t & 63;
    const int w    = t >> 6;
    const int ln   = lane & 15;
    const int quad = lane >> 4;

    const int bid  = blockIdx.x;
    const int dirb = bid & 7;              // one (dir,b) per XCD -> V L2-resident
    const int dir  = dirb >> 2;
    const int b    = dirb & 3;
    const int i0   = (bid >> 3) * 64;

    const bf16* q = qg + ((size_t)dir*BB + b)*SS*DD;
    const bf16* k = kg + ((size_t)(1-dir)*BB + b)*SS*DD;
    const bf16* v = vg + ((size_t)(1-dir)*BB + b)*(size_t)CC*SS;
    float* op = out + ((size_t)dir*BB + b)*(size_t)CC*SS;

    // Q B-frag: B[n=q(ln)][k=d(quad*8+)] — wave's 16 queries
    const bf16x8 bq = *(const bf16x8*)(q + (size_t)(i0 + w*16 + ln)*DD + quad*8);
    // K A-frag base: A[m=key(ln)][k=d(quad*8+)]
    const bf16* kbase = k + (size_t)ln*DD + quad*8;
    // staging: thread t copies 8x16B, linear
    const bf16* vstage = v + w*512 + lane*8;
    char* lds0 = vsm + w*1024;

    f32x4 o[16];
    #pragma unroll
    for (int cb = 0; cb < 16; ++cb) o[cb] = (f32x4){0.f,0.f,0.f,0.f};
    f32x4 lpq = (f32x4){0.f,0.f,0.f,0.f};

    bf16x8 kf[4];
    #pragma unroll
    for (int nb = 0; nb < 4; ++nb)
        kf[nb] = *(const bf16x8*)(kbase + (size_t)(nb*16)*DD);

    #define STAGE(ch, buf) do {                                               \
        const bf16* gp_ = vstage + (size_t)(ch)*CH_ELEM;                      \
        char* lp_ = lds0 + (buf)*32768;                                       \
        _Pragma("unroll")                                                     \
        for (int j = 0; j < 8; ++j)                                           \
            __builtin_amdgcn_global_load_lds(                                 \
                (const __attribute__((address_space(1))) void*)(gp_ + j*2048),\
                (__attribute__((address_space(3))) void*)(lp_ + j*4096),      \
                16, 0, 0);                                                    \
    } while (0)

    #define SMAX(sarr, pa) do {                                               \
        float e_[4][4];                                                       \
        _Pragma("unroll")                                                     \
        for (int nb = 0; nb < 4; ++nb)                                        \
            _Pragma("unroll")                                                 \
            for (int r = 0; r < 4; ++r) {                                     \
                e_[nb][r] = exp2f((sarr)[nb][r]*L2E - SM_C);                   \
                lpq[r] += e_[nb][r];                                          \
            }                                                                 \
        _Pragma("unroll")                                                     \
        for (int ks = 0; ks < 2; ++ks) {                                      \
            u32x4 pk_;                                                        \
            _Pragma("unroll")                                                 \
            for (int jp = 0; jp < 4; ++jp)                                    \
                pk_[jp] = pack2(e_[2*ks + (jp>>1)][2*(jp&1)],                 \
                                e_[2*ks + (jp>>1)][2*(jp&1) + 1]);            \
            (pa)[ks] = __builtin_bit_cast(bf16x8, pk_);                       \
        }                                                                     \
    } while (0)

    bf16x8 paA[2];
    // prologue: S^T(0) -> paA; stage chunks 0,1; kf <- K(1)
    {
        f32x4 s[4];
        #pragma unroll
        for (int nb = 0; nb < 4; ++nb)
            s[nb] = __builtin_amdgcn_mfma_f32_16x16x32_bf16(
                        kf[nb], bq, (f32x4){0.f,0.f,0.f,0.f}, 0, 0, 0);
        STAGE(0, 0);
        STAGE(1, 1);
        #pragma unroll
        for (int nb = 0; nb < 4; ++nb)
            kf[nb] = *(const bf16x8*)(kbase + (size_t)(64 + nb*16)*DD);
        SMAX(s, paA);
    }

    for (int n = 0; n < 64; ++n) {
        // staging(n) complete everywhere; 12 newest (stage n+1 + K n+2) stay
        bar_vm12();

        // PV(n) FIRST: 32 conflict-free ds_read_b128 + 32 MFMA (paA from n-1's
        // SMAX) — issues immediately after the barrier, no VALU prefix
        const char* bufp = vsm + (n & 1)*32768;
        __builtin_amdgcn_s_setprio(1);
        #pragma unroll
        for (int st = 0; st < 32; ++st) {
            const int cb = st & 15;          // ks = st>>4
            const bf16x8 vfr = *(const bf16x8*)(bufp + st*1024 + lane*16);
            o[cb] = __builtin_amdgcn_mfma_f32_16x16x32_bf16(
                        paA[st >> 4], vfr, o[cb], 0, 0, 0);
        }
        __builtin_amdgcn_s_setprio(0);

        // S^T(n+1) (kf = K(n+1)) + K(n+2) prefetch — MFMA queued behind PV
        f32x4 s[4];
        if (n < 63) {
            #pragma unroll
            for (int nb = 0; nb < 4; ++nb)
                s[nb] = __builtin_amdgcn_mfma_f32_16x16x32_bf16(
                            kf[nb], bq, (f32x4){0.f,0.f,0.f,0.f}, 0, 0, 0);
            const int j2 = ((n + 2) & 63) * 64;
            #pragma unroll
            for (int nb = 0; nb < 4; ++nb)
                kf[nb] = *(const bf16x8*)(kbase + (size_t)(j2 + nb*16)*DD);
        }

        bar_plain();                 // all waves done reading buf[n&1]
        if (n < 63)
            STAGE((n + 2) & 63, n & 1);  // refill just-freed buffer

        // SMAX(n+1) -> paA, in the shadow of the next staging wait
        if (n < 63)
            SMAX(s, paA);
    }

    // l per lane: q=ln, keys {16nb+4quad+r} -> fold r, reduce quad copies
    float lp = (lpq[0] + lpq[1]) + (lpq[2] + lpq[3]);
    lp += __shfl_xor(lp, 16);
    lp += __shfl_xor(lp, 32);
    f32x4 ri;
    #pragma unroll
    for (int r = 0; r < 4; ++r)
        ri[r] = 1.0f / __shfl(lp, quad*4 + r);

    // epilogue: fully private, direct stores (row q = i0+w*16+quad*4+r, col c)
    #pragma unroll
    for (int cb = 0; cb < 16; ++cb) {
        const int c = cb*16 + ln;
        float4 val = make_float4(o[cb][0]*ri[0], o[cb][1]*ri[1],
                                 o[cb][2]*ri[2], o[cb][3]*ri[3]);
        *(float4*)(op + (size_t)c*SS + i0 + w*16 + quad*4) = val;
    }
    #undef STAGE
    #undef SMAX
}

// ------------------------------------------------- launch
extern "C" void kernel_launch(void* const* d_in, const int* in_sizes, int n_in,
                              void* d_out, int out_size, void* d_ws, size_t ws_size,
                              hipStream_t stream)
{
    const float* x  = (const float*)d_in[0];
    const float* y  = (const float*)d_in[1];
    const float* Wq = (const float*)d_in[2];
    const float* bq = (const float*)d_in[3];
    const float* Wk = (const float*)d_in[4];
    const float* bk = (const float*)d_in[5];
    const float* Wv = (const float*)d_in[6];
    const float* bv = (const float*)d_in[7];
    float* out = (float*)d_out;
    bf16* ws   = (bf16*)d_ws;

    bf16* qw = ws + Q_OFF;
    bf16* kw = ws + K_OFF;
    bf16* vw = ws + V_OFF;
    bf16* wb = ws + WB_OFF;

    prep_kernel     <<<552, 256, 0, stream>>>(x, y, Wq, Wk, Wv, vw, wb);
    proj_all_kernel <<<512, 256, 0, stream>>>(vw, wb, bq, bk, bv, qw, kw, vw);
    attn_kernel     <<<512, 256, 0, stream>>>(qw, kw, vw, out);
}

// Round 13
// 206.491 us; speedup vs baseline: 1.0834x; 1.0834x over previous
//
#include <hip/hip_runtime.h>

#define BB 4
#define CC 256
#define DD 32
#define SS 4096

typedef __bf16 bf16;
typedef __bf16 bf16x8 __attribute__((ext_vector_type(8)));
typedef __bf16 bf16x4 __attribute__((ext_vector_type(4)));
typedef float f32x4 __attribute__((ext_vector_type(4)));
typedef unsigned int u32;
typedef u32 u32x4 __attribute__((ext_vector_type(4)));
typedef unsigned short u16;

// workspace layout (bf16 elements):
//  q:  [2][BB][SS][DD]  off 0         (pos-major, 32 d inner)
//  k:  [2][BB][SS][DD]  off 1048576
//  v:  [2][BB][...]     off 2097152   chunked B-frag order: V[c][key] at
//       (2*(key>>6) + ks)*8192 + (c>>4)*512 + (quadf*16 + (c&15))*8 + j
//       (kk=key&63, ks=kk>>5, quadf=(kk>>2)&3, j=((kk>>4)&1)*4+(kk&3));
//       each 1 KB fragment lane-contiguous; each 32 KB chunk contiguous.
//  wb: [320][CC]        off 10485760  (bf16 Wq|Wk|Wv stacked)
#define Q_OFF  0
#define K_OFF  1048576
#define V_OFF  2097152
#define WB_OFF 10485760
#define CH_ELEM 16384   // elements per 64-key V chunk (32 KB)

static __device__ __forceinline__ u32 pack2(float lo, float hi) {
    bf16 a = (bf16)lo, b = (bf16)hi;
    u16 ua = __builtin_bit_cast(u16, a), ub = __builtin_bit_cast(u16, b);
    return (u32)ua | ((u32)ub << 16);
}

// staged-buffer barrier: wait until only the 12 newest VMEM ops (next chunk's
// 8 staging + the K prefetch quad) remain in flight (T4 counted-vmcnt).
static __device__ __forceinline__ void bar_vm12() {
    asm volatile("s_waitcnt vmcnt(12)" ::: "memory");
    __builtin_amdgcn_s_barrier();
    asm volatile("" ::: "memory");
}
static __device__ __forceinline__ void bar_plain() {
    asm volatile("" ::: "memory");
    __builtin_amdgcn_s_barrier();
    asm volatile("" ::: "memory");
}

// ------------------------------------------------- W fp32 -> bf16 [320][256]
__global__ __launch_bounds__(256) void convert_w_kernel(
    const float* __restrict__ Wq, const float* __restrict__ Wk,
    const float* __restrict__ Wv, bf16* __restrict__ wb)
{
    const int gid = blockIdx.x*256 + threadIdx.x;    // 40 blocks -> 10240
    const int idx = gid*8;
    const int o = idx >> 8, cc = idx & 255;
    const float* row = (o < 32) ? (Wq + (size_t)o*CC)
                     : (o < 64) ? (Wk + (size_t)(o-32)*CC)
                                : (Wv + (size_t)(o-64)*CC);
    const float4 a = *(const float4*)(row + cc);
    const float4 c = *(const float4*)(row + cc + 4);
    bf16x8 pk;
    pk[0]=(bf16)a.x; pk[1]=(bf16)a.y; pk[2]=(bf16)a.z; pk[3]=(bf16)a.w;
    pk[4]=(bf16)c.x; pk[5]=(bf16)c.y; pk[6]=(bf16)c.z; pk[7]=(bf16)c.w;
    *(bf16x8*)(wb + idx) = pk;
}

// ------------------------------------------------- fused transpose+q,k,v projection
// C[pos][o] = sum_cc X[cc][pos]*W[o][cc] + bias;  o: 0-31 q, 32-63 k, 64-319 v
// The block's X tile (64 pos x 256 cc) is DMA-staged as RAW FP32 into LDS
// (64 KB; 16 x global_load_lds per thread — per-lane global addrs do the
// gather, LDS dest linear), ONE barrier, then each wave free-runs 8 chunks:
// 8x ds_read_b32 (stride 256 B, 4-way conflict ~1.58x) + in-reg f32->bf16
// convert + 20 MFMA + W prefetch. No transpose pass, no X round-trip through
// HBM (R9-R12's split cost ~33.6 MB extra traffic and a launch).
__global__ __launch_bounds__(256, 2) void proj_all_kernel(
    const float* __restrict__ x, const float* __restrict__ y,
    const bf16* __restrict__ wb,
    const float* __restrict__ bq, const float* __restrict__ bk,
    const float* __restrict__ bv,
    bf16* __restrict__ qout, bf16* __restrict__ kout, bf16* __restrict__ vout)
{
    __shared__ __align__(16) char xsm[65536];   // f32 tile [256 cc][64 pos]

    const int t    = threadIdx.x;
    const int lane = t & 63;
    const int w    = t >> 6;
    const int ln   = lane & 15;
    const int quad = lane >> 4;

    const int bid  = blockIdx.x;
    const int dirb = bid & 7;
    const int src  = dirb >> 2;
    const int b    = dirb & 3;
    const int tile = bid >> 3;
    const int i0   = tile * 64;

    const float* in = (src ? y : x) + (size_t)b*CC*SS + tile*64;

    // DMA stage: round r covers cc = r*16 + (t>>4), pos4 = (t&15)*4..+3.
    // LDS dword addr = cc*64 + pos -> offset t*16 B within round slab.
    {
        const int pos4 = (t & 15) * 4;
        const int ccw  = t >> 4;                  // 0..15 within round
        char* ldsb = xsm + w*1024;                // wave-uniform base (+r*4096)
        #pragma unroll
        for (int r = 0; r < 16; ++r)
            __builtin_amdgcn_global_load_lds(
                (const __attribute__((address_space(1))) void*)
                    (in + (size_t)(r*16 + ccw)*SS + pos4),
                (__attribute__((address_space(3))) void*)(ldsb + r*4096),
                16, 0, 0);
    }

    float bias[5];
    #pragma unroll
    for (int nbl = 0; nbl < 5; ++nbl) {
        const int o = 80*w + nbl*16 + ln;
        bias[nbl] = (o < 32) ? bq[o] : (o < 64) ? bk[o-32] : bv[o-64];
    }
    const bf16* wrow = wb + (size_t)(80*w + ln)*CC + quad*8;
    bf16x8 bf[5];
    #pragma unroll
    for (int nbl = 0; nbl < 5; ++nbl)
        bf[nbl] = *(const bf16x8*)(wrow + (size_t)nbl*16*CC);

    f32x4 acc[4][5];
    #pragma unroll
    for (int mb = 0; mb < 4; ++mb)
        #pragma unroll
        for (int nbl = 0; nbl < 5; ++nbl)
            acc[mb][nbl] = (f32x4){bias[nbl], bias[nbl], bias[nbl], bias[nbl]};

    __syncthreads();   // DMA complete (one-shot drain is fine here)

    const float* xr = (const float*)xsm;          // [cc][64 pos]
    for (int n = 0; n < 8; ++n) {
        bf16x8 af[4];
        #pragma unroll
        for (int mb = 0; mb < 4; ++mb) {
            float f[8];
            #pragma unroll
            for (int j = 0; j < 8; ++j)
                f[j] = xr[(n*32 + quad*8 + j)*64 + mb*16 + ln];
            #pragma unroll
            for (int j = 0; j < 8; ++j) af[mb][j] = (bf16)f[j];
        }
        #pragma unroll
        for (int mb = 0; mb < 4; ++mb)
            #pragma unroll
            for (int nbl = 0; nbl < 5; ++nbl)
                acc[mb][nbl] = __builtin_amdgcn_mfma_f32_16x16x32_bf16(
                                   af[mb], bf[nbl], acc[mb][nbl], 0, 0, 0);
        // prefetch next W chunk (wrap at tail: redundant, in-bounds)
        const int ccn = ((n+1)*32) & 255;
        #pragma unroll
        for (int nbl = 0; nbl < 5; ++nbl)
            bf[nbl] = *(const bf16x8*)(wrow + (size_t)nbl*16*CC + ccn);
    }

    bf16* qo = qout + (size_t)(src*BB + b)*SS*DD;
    bf16* ko = kout + (size_t)(src*BB + b)*SS*DD;
    bf16* vo = vout + (size_t)(src*BB + b)*CC*SS;
    const int n0 = tile;
    #pragma unroll
    for (int nbl = 0; nbl < 5; ++nbl) {
        const int o = 80*w + nbl*16 + ln;
        if (o < 32) {
            #pragma unroll
            for (int mb = 0; mb < 4; ++mb)
                #pragma unroll
                for (int r = 0; r < 4; ++r)
                    qo[(size_t)(i0 + mb*16 + quad*4 + r)*DD + o] = (bf16)acc[mb][nbl][r];
        } else if (o < 64) {
            #pragma unroll
            for (int mb = 0; mb < 4; ++mb)
                #pragma unroll
                for (int r = 0; r < 4; ++r)
                    ko[(size_t)(i0 + mb*16 + quad*4 + r)*DD + (o-32)] = (bf16)acc[mb][nbl][r];
        } else {
            const int c = o - 64;
            const int cb = c >> 4, cl = c & 15;
            // pos = i0+mb*16+quad*4+r -> chunk n0, ks=mb>>1, j=(mb&1)*4+r,
            // quadf=quad -> contiguous bf16x4 store within lane's 16B slot
            #pragma unroll
            for (int mb = 0; mb < 4; ++mb) {
                bf16x4 pk;
                #pragma unroll
                for (int r = 0; r < 4; ++r) pk[r] = (bf16)acc[mb][nbl][r];
                *(bf16x4*)(vo + (size_t)(2*n0 + (mb>>1))*8192 + cb*512
                              + (quad*16 + cl)*8 + (mb&1)*4) = pk;
            }
        }
    }
}

// ------------------------------------------------- attention (LDS-staged V, private P)
// R11 verified structure (119.7 us, MfmaUtil 28%, 0 conflicts, VGPR 88):
// bar_vm12 -> PV(n) [ds_read+MFMA issue immediately] -> S^T(n+1) -> bar_plain
// -> STAGE(n+2) -> SMAX(n+1) (in the shadow of the next staging wait).
#define L2E   1.4426950408889634f
#define SM_C  (16.0f * L2E)

__global__ __launch_bounds__(256, 2) void attn_kernel(
    const bf16* __restrict__ qg, const bf16* __restrict__ kg,
    const bf16* __restrict__ vg, float* __restrict__ out)
{
    __shared__ __align__(16) char vsm[2*32768];   // V chunk double buffer

    const int t    = threadIdx.x;
    const int lane = t & 63;
    const int w    = t >> 6;
    const int ln   = lane & 15;
    const int quad = lane >> 4;

    const int bid  = blockIdx.x;
    const int dirb = bid & 7;              // one (dir,b) per XCD -> V L2-resident
    const int dir  = dirb >> 2;
    const int b    = dirb & 3;
    const int i0   = (bid >> 3) * 64;

    const bf16* q = qg + ((size_t)dir*BB + b)*SS*DD;
    const bf16* k = kg + ((size_t)(1-dir)*BB + b)*SS*DD;
    const bf16* v = vg + ((size_t)(1-dir)*BB + b)*(size_t)CC*SS;
    float* op = out + ((size_t)dir*BB + b)*(size_t)CC*SS;

    // Q B-frag: B[n=q(ln)][k=d(quad*8+)] — wave's 16 queries
    const bf16x8 bq = *(const bf16x8*)(q + (size_t)(i0 + w*16 + ln)*DD + quad*8);
    // K A-frag base: A[m=key(ln)][k=d(quad*8+)]
    const bf16* kbase = k + (size_t)ln*DD + quad*8;
    // staging: thread t copies 8x16B, linear
    const bf16* vstage = v + w*512 + lane*8;
    char* lds0 = vsm + w*1024;

    f32x4 o[16];
    #pragma unroll
    for (int cb = 0; cb < 16; ++cb) o[cb] = (f32x4){0.f,0.f,0.f,0.f};
    f32x4 lpq = (f32x4){0.f,0.f,0.f,0.f};

    bf16x8 kf[4];
    #pragma unroll
    for (int nb = 0; nb < 4; ++nb)
        kf[nb] = *(const bf16x8*)(kbase + (size_t)(nb*16)*DD);

    #define STAGE(ch, buf) do {                                               \
        const bf16* gp_ = vstage + (size_t)(ch)*CH_ELEM;                      \
        char* lp_ = lds0 + (buf)*32768;                                       \
        _Pragma("unroll")                                                     \
        for (int j = 0; j < 8; ++j)                                           \
            __builtin_amdgcn_global_load_lds(                                 \
                (const __attribute__((address_space(1))) void*)(gp_ + j*2048),\
                (__attribute__((address_space(3))) void*)(lp_ + j*4096),      \
                16, 0, 0);                                                    \
    } while (0)

    #define SMAX(sarr, pa) do {                                               \
        float e_[4][4];                                                       \
        _Pragma("unroll")                                                     \
        for (int nb = 0; nb < 4; ++nb)                                        \
            _Pragma("unroll")                                                 \
            for (int r = 0; r < 4; ++r) {                                     \
                e_[nb][r] = exp2f((sarr)[nb][r]*L2E - SM_C);                   \
                lpq[r] += e_[nb][r];                                          \
            }                                                                 \
        _Pragma("unroll")                                                     \
        for (int ks = 0; ks < 2; ++ks) {                                      \
            u32x4 pk_;                                                        \
            _Pragma("unroll")                                                 \
            for (int jp = 0; jp < 4; ++jp)                                    \
                pk_[jp] = pack2(e_[2*ks + (jp>>1)][2*(jp&1)],                 \
                                e_[2*ks + (jp>>1)][2*(jp&1) + 1]);            \
            (pa)[ks] = __builtin_bit_cast(bf16x8, pk_);                       \
        }                                                                     \
    } while (0)

    bf16x8 paA[2];
    // prologue: S^T(0) -> paA; stage chunks 0,1; kf <- K(1)
    {
        f32x4 s[4];
        #pragma unroll
        for (int nb = 0; nb < 4; ++nb)
            s[nb] = __builtin_amdgcn_mfma_f32_16x16x32_bf16(
                        kf[nb], bq, (f32x4){0.f,0.f,0.f,0.f}, 0, 0, 0);
        STAGE(0, 0);
        STAGE(1, 1);
        #pragma unroll
        for (int nb = 0; nb < 4; ++nb)
            kf[nb] = *(const bf16x8*)(kbase + (size_t)(64 + nb*16)*DD);
        SMAX(s, paA);
    }

    for (int n = 0; n < 64; ++n) {
        // staging(n) complete everywhere; 12 newest (stage n+1 + K n+2) stay
        bar_vm12();

        // PV(n) FIRST: 32 conflict-free ds_read_b128 + 32 MFMA (paA from n-1's
        // SMAX) — issues immediately after the barrier, no VALU prefix
        const char* bufp = vsm + (n & 1)*32768;
        __builtin_amdgcn_s_setprio(1);
        #pragma unroll
        for (int st = 0; st < 32; ++st) {
            const int cb = st & 15;          // ks = st>>4
            const bf16x8 vfr = *(const bf16x8*)(bufp + st*1024 + lane*16);
            o[cb] = __builtin_amdgcn_mfma_f32_16x16x32_bf16(
                        paA[st >> 4], vfr, o[cb], 0, 0, 0);
        }
        __builtin_amdgcn_s_setprio(0);

        // S^T(n+1) (kf = K(n+1)) + K(n+2) prefetch — MFMA queued behind PV
        f32x4 s[4];
        if (n < 63) {
            #pragma unroll
            for (int nb = 0; nb < 4; ++nb)
                s[nb] = __builtin_amdgcn_mfma_f32_16x16x32_bf16(
                            kf[nb], bq, (f32x4){0.f,0.f,0.f,0.f}, 0, 0, 0);
            const int j2 = ((n + 2) & 63) * 64;
            #pragma unroll
            for (int nb = 0; nb < 4; ++nb)
                kf[nb] = *(const bf16x8*)(kbase + (size_t)(j2 + nb*16)*DD);
        }

        bar_plain();                 // all waves done reading buf[n&1]
        if (n < 63)
            STAGE((n + 2) & 63, n & 1);  // refill just-freed buffer

        // SMAX(n+1) -> paA, in the shadow of the next staging wait
        if (n < 63)
            SMAX(s, paA);
    }

    // l per lane: q=ln, keys {16nb+4quad+r} -> fold r, reduce quad copies
    float lp = (lpq[0] + lpq[1]) + (lpq[2] + lpq[3]);
    lp += __shfl_xor(lp, 16);
    lp += __shfl_xor(lp, 32);
    f32x4 ri;
    #pragma unroll
    for (int r = 0; r < 4; ++r)
        ri[r] = 1.0f / __shfl(lp, quad*4 + r);

    // epilogue: fully private, direct stores (row q = i0+w*16+quad*4+r, col c)
    #pragma unroll
    for (int cb = 0; cb < 16; ++cb) {
        const int c = cb*16 + ln;
        float4 val = make_float4(o[cb][0]*ri[0], o[cb][1]*ri[1],
                                 o[cb][2]*ri[2], o[cb][3]*ri[3]);
        *(float4*)(op + (size_t)c*SS + i0 + w*16 + quad*4) = val;
    }
    #undef STAGE
    #undef SMAX
}

// ------------------------------------------------- launch
extern "C" void kernel_launch(void* const* d_in, const int* in_sizes, int n_in,
                              void* d_out, int out_size, void* d_ws, size_t ws_size,
                              hipStream_t stream)
{
    const float* x  = (const float*)d_in[0];
    const float* y  = (const float*)d_in[1];
    const float* Wq = (const float*)d_in[2];
    const float* bq = (const float*)d_in[3];
    const float* Wk = (const float*)d_in[4];
    const float* bk = (const float*)d_in[5];
    const float* Wv = (const float*)d_in[6];
    const float* bv = (const float*)d_in[7];
    float* out = (float*)d_out;
    bf16* ws   = (bf16*)d_ws;

    bf16* qw = ws + Q_OFF;
    bf16* kw = ws + K_OFF;
    bf16* vw = ws + V_OFF;
    bf16* wb = ws + WB_OFF;

    convert_w_kernel<<<40,  256, 0, stream>>>(Wq, Wk, Wv, wb);
    proj_all_kernel <<<512, 256, 0, stream>>>(x, y, wb, bq, bk, bv, qw, kw, vw);
    attn_kernel     <<<512, 256, 0, stream>>>(qw, kw, vw, out);
}